// Round 1
// baseline (1528.539 us; speedup 1.0000x reference)
//
#include <hip/hip_runtime.h>
#include <hip/hip_bf16.h>

#define B_GRAPHS 64
#define NPER     2048
#define T_NODES  (B_GRAPHS*NPER)
#define D_DIM    256
#define U_DIM    128
#define TU       384   // 3*U
#define XPW      768   // 2*TU (fwd|bwd)

typedef unsigned short ushortT;
typedef unsigned int   uint32;

typedef __attribute__((ext_vector_type(4))) float  f32x4;
typedef __attribute__((ext_vector_type(8))) __bf16 bf16x8;
typedef _Float16 f16;
typedef __attribute__((ext_vector_type(2))) _Float16 f16x2;

static __device__ __forceinline__ ushortT f2bf(float f) {
  union { float f; uint32 u; } a; a.f = f;
  uint32 u = a.u;
  return (ushortT)((u + 0x7fffu + ((u >> 16) & 1u)) >> 16);   // RTNE
}
static __device__ __forceinline__ float bf2f(ushortT h) {
  union { uint32 u; float f; } a; a.u = ((uint32)h) << 16; return a.f;
}
static __device__ __forceinline__ f16x2 u2h(uint32 u) {
  union { uint32 u; f16x2 h; } x; x.u = u; return x.h;
}
static __device__ __forceinline__ float dot2f(f16x2 a, f16x2 b, float c) {
#if __has_builtin(__builtin_amdgcn_fdot2)
  return __builtin_amdgcn_fdot2(a, b, c, false);
#else
  return c + (float)a.x * (float)b.x + (float)a.y * (float)b.y;
#endif
}

// ---------------- prep: Wt[2][768][256] bf16 (transposed concat of K_fwd|K_bwd), b0[2][768] f32
__global__ __launch_bounds__(256) void prep_kernel(
    const float* __restrict__ Kf, const float* __restrict__ Kb,
    const float* __restrict__ bfw, const float* __restrict__ bbw,
    ushortT* __restrict__ Wt, float* __restrict__ b0)
{
  int idx = blockIdx.x * 256 + threadIdx.x;
  if (idx < 2 * XPW * D_DIM) {
    int l = idx / (XPW * D_DIM);
    int rem = idx % (XPW * D_DIM);
    int c = rem / D_DIM, k = rem % D_DIM;
    float v = (c < TU) ? Kf[(size_t)l * D_DIM * TU + (size_t)k * TU + c]
                       : Kb[(size_t)l * D_DIM * TU + (size_t)k * TU + (c - TU)];
    Wt[idx] = f2bf(v);
  } else {
    int i2 = idx - 2 * XPW * D_DIM;
    if (i2 < 2 * XPW) {
      int l = i2 / XPW, c = i2 % XPW;
      b0[i2] = (c < TU) ? bfw[l * 2 * TU + c] : bbw[l * 2 * TU + (c - TU)];
    }
  }
}

// ---------------- nodeof[g][slot] = node index ; L[g] = leaf count (positions are a perm of 1..L)
__global__ __launch_bounds__(256) void nodeofL_kernel(
    const int* __restrict__ pos, int* __restrict__ nodeof, int* __restrict__ L)
{
  int g = blockIdx.x, tid = threadIdx.x;
  __shared__ int red[256];
  int cnt = 0;
  for (int i = 0; i < NPER / 256; ++i) {
    int t = g * NPER + i * 256 + tid;
    int p = pos[t];
    if (p) { nodeof[g * NPER + p - 1] = t; cnt++; }
  }
  red[tid] = cnt; __syncthreads();
  for (int s = 128; s > 0; s >>= 1) {
    if (tid < s) red[tid] += red[tid + s];
    __syncthreads();
  }
  if (tid == 0) L[g] = red[0];
}

#if __has_builtin(__builtin_amdgcn_global_load_lds)
#define GLD_LDS(gsrc, ldst) \
  __builtin_amdgcn_global_load_lds((const __attribute__((address_space(1))) void*)(gsrc), \
                                   (__attribute__((address_space(3))) void*)(ldst), 16, 0, 0)
#define HAVE_GLD_LDS 1
#else
#define HAVE_GLD_LDS 0
#endif

// ---------------- xp[row][768] = A[row][0..255] @ Wt^T + b0   (bf16 MFMA, 128x128 tiles, BK=32)
// mode 0: A row r gathered from states (f32 -> bf16) via nodeof ; mode 1: A = dense bf16 (y)
__global__ __launch_bounds__(256) void gemm_kernel(
    const float* __restrict__ statesA, const ushortT* __restrict__ Adense,
    const ushortT* __restrict__ Wt, const float* __restrict__ b0,
    const int* __restrict__ nodeof, const int* __restrict__ L,
    ushortT* __restrict__ xp, int layer, int mode)
{
  int mblk = blockIdx.x, nblk = blockIdx.y;
  int g = mblk >> 4;
  int sBase = (mblk & 15) << 7;
  int Lg = L[g];
  if (sBase >= Lg) return;   // whole row-block is padding

  __shared__ __align__(16) ushortT As[128 * 32];
  __shared__ __align__(16) ushortT Bs[128 * 32];

  int tid = threadIdx.x;
  int lane = tid & 63, wid = tid >> 6;
  int wr = wid >> 1, wc = wid & 1;
  f32x4 acc[4][4];
  for (int i = 0; i < 4; i++) for (int n = 0; n < 4; n++) acc[i][n] = (f32x4){0.f,0.f,0.f,0.f};

  for (int kb = 0; kb < 8; ++kb) {
    __syncthreads();
    // stage B: Wt tile [128 cols][32 k] (Wt is pre-transposed: row=col, 512B row stride)
    for (int c = 0; c < 2; ++c) {
      int flat = c * 4096 + tid * 16;
      int col = flat >> 6;
      size_t srcB = ((size_t)(layer * XPW + nblk * 128 + col)) * 512 + kb * 64 + (flat & 63);
#if HAVE_GLD_LDS
      GLD_LDS((const char*)Wt + srcB, (char*)Bs + c * 4096 + wid * 1024);
#else
      *(uint4*)((char*)Bs + flat) = *(const uint4*)((const char*)Wt + srcB);
#endif
    }
    // stage A
    if (mode) {
      for (int c = 0; c < 2; ++c) {
        int flat = c * 4096 + tid * 16;
        int row = flat >> 6;
        size_t srcA = ((size_t)(mblk * 128 + row)) * 512 + kb * 64 + (flat & 63);
#if HAVE_GLD_LDS
        GLD_LDS((const char*)Adense + srcA, (char*)As + c * 4096 + wid * 1024);
#else
        *(uint4*)((char*)As + flat) = *(const uint4*)((const char*)Adense + srcA);
#endif
      }
    } else {
      for (int c = 0; c < 2; ++c) {
        int flat = c * 4096 + tid * 16;
        int row = flat >> 6;
        int s = sBase + row;
        if (s < Lg) {
          int nt = nodeof[g * NPER + s];
          const float* sp = statesA + (size_t)nt * D_DIM + kb * 32 + ((flat & 63) >> 1);
          float4 u0 = *(const float4*)sp;
          float4 u1 = *(const float4*)(sp + 4);
          union { ushortT us[8]; uint4 v; } pk;
          pk.us[0] = f2bf(u0.x); pk.us[1] = f2bf(u0.y); pk.us[2] = f2bf(u0.z); pk.us[3] = f2bf(u0.w);
          pk.us[4] = f2bf(u1.x); pk.us[5] = f2bf(u1.y); pk.us[6] = f2bf(u1.z); pk.us[7] = f2bf(u1.w);
          *(uint4*)((char*)As + flat) = pk.v;
        }
      }
    }
    __syncthreads();

    bf16x8 af[4], bfr[4];
    for (int i = 0; i < 4; i++) {
      int off = (wr * 64 + i * 16 + (lane & 15)) * 32 + (lane >> 4) * 8;
      af[i] = *(const bf16x8*)&As[off];
    }
    for (int n = 0; n < 4; n++) {
      int off = (wc * 64 + n * 16 + (lane & 15)) * 32 + (lane >> 4) * 8;
      bfr[n] = *(const bf16x8*)&Bs[off];
    }
    for (int i = 0; i < 4; i++)
      for (int n = 0; n < 4; n++)
        acc[i][n] = __builtin_amdgcn_mfma_f32_16x16x32_bf16(af[i], bfr[n], acc[i][n], 0, 0, 0);
  }

  // epilogue: + bias, store bf16.  C/D layout: col = lane&15, row = (lane>>4)*4 + v
  for (int n = 0; n < 4; n++) {
    int gcol = nblk * 128 + wc * 64 + n * 16 + (lane & 15);
    float bb = b0[layer * XPW + gcol];
    for (int i = 0; i < 4; i++) {
      int rowBase = mblk * 128 + wr * 64 + i * 16 + (lane >> 4) * 4;
      for (int v = 0; v < 4; v++)
        xp[(size_t)(rowBase + v) * XPW + gcol] = f2bf(acc[i][n][v] + bb);
    }
  }
}

// ---------------- recurrence: 1 workgroup per (graph, dir); 768 threads = (col 0..383) x (k-half 0..1)
__global__ __launch_bounds__(768) void rec_kernel(
    const ushortT* __restrict__ xp,
    const float* __restrict__ Rf, const float* __restrict__ Rb,
    const float* __restrict__ bfw, const float* __restrict__ bbw,
    const int* __restrict__ L, ushortT* __restrict__ y, int layer)
{
  int g = blockIdx.x, dir = blockIdx.y;
  int Lg = L[g];
  if (Lg == 0) return;
  int tid = threadIdx.x;
  int col = tid % TU;
  int khalf = tid / TU;

  __shared__ __align__(16) f16 hpk[128];   // h state, f16-packed, for the matvec
  __shared__ float hp[768];                // matvec partials

  const float* R = (dir ? Rb : Rf) + (size_t)layer * U_DIM * TU;
  f16x2 rr[32];
  #pragma unroll
  for (int m = 0; m < 32; ++m) {
    int k = khalf * 64 + 2 * m;
    f16x2 p;
    p.x = (f16)R[(size_t)k * TU + col];
    p.y = (f16)R[(size_t)(k + 1) * TU + col];
    rr[m] = p;
  }
  float b1col = (dir ? bbw : bfw)[layer * 2 * TU + TU + col];
  float accInit = khalf ? 0.0f : b1col;

  if (tid < 128) hpk[tid] = (f16)0.0f;
  float hreg = 0.0f;
  __syncthreads();

  int j = tid;  // gate lane id when < 128
  ushortT xzu = 0, xru = 0, xhu = 0;
  size_t xbase = (size_t)g * NPER * XPW + (size_t)dir * TU;
  if (tid < 128) {
    int pos = dir ? (Lg - 1) : 0;
    const ushortT* p = xp + xbase + (size_t)pos * XPW + j;
    xzu = p[0]; xru = p[128]; xhu = p[256];
  }

  for (int s = 0; s < Lg; ++s) {
    // --- matvec: hp_partial[col,khalf] = sum_k h[k]*R[k][col] (+b1 on khalf 0)
    float a0 = accInit, a1 = 0.0f;
    const uint4* hv = (const uint4*)&hpk[khalf * 64];
    #pragma unroll
    for (int m4 = 0; m4 < 8; ++m4) {
      uint4 q = hv[m4];
      a0 = dot2f(u2h(q.x), rr[4 * m4 + 0], a0);
      a1 = dot2f(u2h(q.y), rr[4 * m4 + 1], a1);
      a0 = dot2f(u2h(q.z), rr[4 * m4 + 2], a0);
      a1 = dot2f(u2h(q.w), rr[4 * m4 + 3], a1);
    }
    hp[tid] = a0 + a1;
    __syncthreads();

    if (tid < 128) {
      int pos = dir ? (Lg - 1 - s) : s;
      float hz = hp[j]       + hp[TU + j];
      float hr = hp[128 + j] + hp[TU + 128 + j];
      float hh = hp[256 + j] + hp[TU + 256 + j];
      float xz = bf2f(xzu), xr = bf2f(xru), xh = bf2f(xhu);
      float z = 1.0f / (1.0f + __expf(-(xz + hz)));
      float r = 1.0f / (1.0f + __expf(-(xr + hr)));
      float ch = xh + r * hh;
      float e = __expf(2.0f * fabsf(ch));
      float th = 1.0f - 2.0f / (e + 1.0f);
      float cand = (ch >= 0.0f) ? th : -th;
      float hnew = z * hreg + (1.0f - z) * cand;
      hreg = hnew;
      hpk[j] = (f16)hnew;
      y[(size_t)(g * NPER + pos) * D_DIM + dir * U_DIM + j] = f2bf(hnew);
      int s2 = s + 1;
      if (s2 < Lg) {
        int pos2 = dir ? (Lg - 1 - s2) : s2;
        const ushortT* p = xp + xbase + (size_t)pos2 * XPW + j;
        xzu = p[0]; xru = p[128]; xhu = p[256];
      }
    }
    __syncthreads();
  }
}

// ---------------- unpack: leaf -> y (bf16->f32), non-leaf -> states copy
__global__ __launch_bounds__(256) void unpack_kernel(
    const float* __restrict__ states, const int* __restrict__ pos,
    const ushortT* __restrict__ y, float* __restrict__ out)
{
  int node = blockIdx.x * 4 + (threadIdx.x >> 6);
  int lane = threadIdx.x & 63;
  int p = pos[node];
  int g = node >> 11;
  float4 v;
  if (p) {
    const ushortT* yp = y + (size_t)(g * NPER + p - 1) * D_DIM + lane * 4;
    v = make_float4(bf2f(yp[0]), bf2f(yp[1]), bf2f(yp[2]), bf2f(yp[3]));
  } else {
    v = *(const float4*)(states + (size_t)node * D_DIM + lane * 4);
  }
  *(float4*)(out + (size_t)node * D_DIM + lane * 4) = v;
}

extern "C" void kernel_launch(void* const* d_in, const int* in_sizes, int n_in,
                              void* d_out, int out_size, void* d_ws, size_t ws_size,
                              hipStream_t stream) {
  const float* states = (const float*)d_in[0];
  const int*   pos    = (const int*)d_in[1];
  // d_in[2] graph_sizes (uniform 2048), d_in[3] training (0) — unused
  const float* Kf  = (const float*)d_in[4];
  const float* Rf  = (const float*)d_in[5];
  const float* bfw = (const float*)d_in[6];
  const float* Kb  = (const float*)d_in[7];
  const float* Rb  = (const float*)d_in[8];
  const float* bbw = (const float*)d_in[9];

  char* ws = (char*)d_ws;
  // layout: L(256B) | nodeof(512KB) | Wt(768KB) | b0(6KB) | xp(201.3MB) | y(67.1MB)  ~= 270MB
  int*     L      = (int*)(ws + 0);
  int*     nodeof = (int*)(ws + 256);
  ushortT* Wt     = (ushortT*)(ws + 524544);
  float*   b0     = (float*)(ws + 1310976);
  ushortT* xp     = (ushortT*)(ws + 1317120);
  ushortT* y      = (ushortT*)(ws + 202643712);

  prep_kernel<<<1542, 256, 0, stream>>>(Kf, Kb, bfw, bbw, Wt, b0);
  nodeofL_kernel<<<64, 256, 0, stream>>>(pos, nodeof, L);

  dim3 ggrid(1024, 6);
  dim3 rgrid(64, 2);

  // layer 0
  gemm_kernel<<<ggrid, 256, 0, stream>>>(states, (const ushortT*)nullptr, Wt, b0, nodeof, L, xp, 0, 0);
  rec_kernel<<<rgrid, 768, 0, stream>>>(xp, Rf, Rb, bfw, bbw, L, y, 0);
  // layer 1
  gemm_kernel<<<ggrid, 256, 0, stream>>>(states, y, Wt, b0, nodeof, L, xp, 1, 1);
  rec_kernel<<<rgrid, 768, 0, stream>>>(xp, Rf, Rb, bfw, bbw, L, y, 1);

  unpack_kernel<<<32768, 256, 0, stream>>>(states, pos, y, (float*)d_out);
}

// Round 2
// 1297.741 us; speedup vs baseline: 1.1778x; 1.1778x over previous
//
#include <hip/hip_runtime.h>
#include <hip/hip_bf16.h>

#define B_GRAPHS 64
#define NPER     2048
#define T_NODES  (B_GRAPHS*NPER)
#define D_DIM    256
#define U_DIM    128
#define TU       384   // 3*U
#define XPW      768   // 2*TU (fwd|bwd)

typedef unsigned short ushortT;
typedef unsigned int   uint32;

typedef __attribute__((ext_vector_type(4))) float  f32x4;
typedef __attribute__((ext_vector_type(8))) __bf16 bf16x8;
typedef _Float16 f16;
typedef __attribute__((ext_vector_type(2))) _Float16 f16x2;

static __device__ __forceinline__ ushortT f2bf(float f) {
  union { float f; uint32 u; } a; a.f = f;
  uint32 u = a.u;
  return (ushortT)((u + 0x7fffu + ((u >> 16) & 1u)) >> 16);   // RTNE
}
static __device__ __forceinline__ float bf2f(ushortT h) {
  union { uint32 u; float f; } a; a.u = ((uint32)h) << 16; return a.f;
}
static __device__ __forceinline__ f16x2 u2h(uint32 u) {
  union { uint32 u; f16x2 h; } x; x.u = u; return x.h;
}
static __device__ __forceinline__ float dot2f(f16x2 a, f16x2 b, float c) {
#if __has_builtin(__builtin_amdgcn_fdot2)
  return __builtin_amdgcn_fdot2(a, b, c, false);
#else
  return c + (float)a.x * (float)b.x + (float)a.y * (float)b.y;
#endif
}
static __device__ __forceinline__ float rcpf(float x) {
#if __has_builtin(__builtin_amdgcn_rcpf)
  return __builtin_amdgcn_rcpf(x);
#else
  return 1.0f / x;
#endif
}

// ---------------- prep: Wt[2][768][256] bf16 (transposed concat of K_fwd|K_bwd), b0[2][768] f32
__global__ __launch_bounds__(256) void prep_kernel(
    const float* __restrict__ Kf, const float* __restrict__ Kb,
    const float* __restrict__ bfw, const float* __restrict__ bbw,
    ushortT* __restrict__ Wt, float* __restrict__ b0)
{
  int idx = blockIdx.x * 256 + threadIdx.x;
  if (idx < 2 * XPW * D_DIM) {
    int l = idx / (XPW * D_DIM);
    int rem = idx % (XPW * D_DIM);
    int c = rem / D_DIM, k = rem % D_DIM;
    float v = (c < TU) ? Kf[(size_t)l * D_DIM * TU + (size_t)k * TU + c]
                       : Kb[(size_t)l * D_DIM * TU + (size_t)k * TU + (c - TU)];
    Wt[idx] = f2bf(v);
  } else {
    int i2 = idx - 2 * XPW * D_DIM;
    if (i2 < 2 * XPW) {
      int l = i2 / XPW, c = i2 % XPW;
      b0[i2] = (c < TU) ? bfw[l * 2 * TU + c] : bbw[l * 2 * TU + (c - TU)];
    }
  }
}

// ---------------- nodeof[g][slot] = node index ; L[g] = leaf count (positions are a perm of 1..L)
__global__ __launch_bounds__(256) void nodeofL_kernel(
    const int* __restrict__ pos, int* __restrict__ nodeof, int* __restrict__ L)
{
  int g = blockIdx.x, tid = threadIdx.x;
  __shared__ int red[256];
  int cnt = 0;
  for (int i = 0; i < NPER / 256; ++i) {
    int t = g * NPER + i * 256 + tid;
    int p = pos[t];
    if (p) { nodeof[g * NPER + p - 1] = t; cnt++; }
  }
  red[tid] = cnt; __syncthreads();
  for (int s = 128; s > 0; s >>= 1) {
    if (tid < s) red[tid] += red[tid + s];
    __syncthreads();
  }
  if (tid == 0) L[g] = red[0];
}

#if __has_builtin(__builtin_amdgcn_global_load_lds)
#define GLD_LDS(gsrc, ldst) \
  __builtin_amdgcn_global_load_lds((const __attribute__((address_space(1))) void*)(gsrc), \
                                   (__attribute__((address_space(3))) void*)(ldst), 16, 0, 0)
#define HAVE_GLD_LDS 1
#else
#define HAVE_GLD_LDS 0
#endif

// ---------------- xp[row][768] = A[row][0..255] @ Wt^T + b0   (bf16 MFMA, 128x128 tiles, BK=32)
// mode 0: A row r gathered from states (f32 -> bf16) via nodeof ; mode 1: A = dense bf16 (y)
__global__ __launch_bounds__(256) void gemm_kernel(
    const float* __restrict__ statesA, const ushortT* __restrict__ Adense,
    const ushortT* __restrict__ Wt, const float* __restrict__ b0,
    const int* __restrict__ nodeof, const int* __restrict__ L,
    ushortT* __restrict__ xp, int layer, int mode)
{
  int mblk = blockIdx.x, nblk = blockIdx.y;
  int g = mblk >> 4;
  int sBase = (mblk & 15) << 7;
  int Lg = L[g];
  if (sBase >= Lg) return;   // whole row-block is padding

  __shared__ __align__(16) ushortT As[128 * 32];
  __shared__ __align__(16) ushortT Bs[128 * 32];

  int tid = threadIdx.x;
  int lane = tid & 63, wid = tid >> 6;
  int wr = wid >> 1, wc = wid & 1;
  f32x4 acc[4][4];
  for (int i = 0; i < 4; i++) for (int n = 0; n < 4; n++) acc[i][n] = (f32x4){0.f,0.f,0.f,0.f};

  for (int kb = 0; kb < 8; ++kb) {
    __syncthreads();
    // stage B: Wt tile [128 cols][32 k] (Wt is pre-transposed: row=col, 512B row stride)
    for (int c = 0; c < 2; ++c) {
      int flat = c * 4096 + tid * 16;
      int col = flat >> 6;
      size_t srcB = ((size_t)(layer * XPW + nblk * 128 + col)) * 512 + kb * 64 + (flat & 63);
#if HAVE_GLD_LDS
      GLD_LDS((const char*)Wt + srcB, (char*)Bs + c * 4096 + wid * 1024);
#else
      *(uint4*)((char*)Bs + flat) = *(const uint4*)((const char*)Wt + srcB);
#endif
    }
    // stage A
    if (mode) {
      for (int c = 0; c < 2; ++c) {
        int flat = c * 4096 + tid * 16;
        int row = flat >> 6;
        size_t srcA = ((size_t)(mblk * 128 + row)) * 512 + kb * 64 + (flat & 63);
#if HAVE_GLD_LDS
        GLD_LDS((const char*)Adense + srcA, (char*)As + c * 4096 + wid * 1024);
#else
        *(uint4*)((char*)As + flat) = *(const uint4*)((const char*)Adense + srcA);
#endif
      }
    } else {
      for (int c = 0; c < 2; ++c) {
        int flat = c * 4096 + tid * 16;
        int row = flat >> 6;
        int s = sBase + row;
        if (s < Lg) {
          int nt = nodeof[g * NPER + s];
          const float* sp = statesA + (size_t)nt * D_DIM + kb * 32 + ((flat & 63) >> 1);
          float4 u0 = *(const float4*)sp;
          float4 u1 = *(const float4*)(sp + 4);
          union { ushortT us[8]; uint4 v; } pk;
          pk.us[0] = f2bf(u0.x); pk.us[1] = f2bf(u0.y); pk.us[2] = f2bf(u0.z); pk.us[3] = f2bf(u0.w);
          pk.us[4] = f2bf(u1.x); pk.us[5] = f2bf(u1.y); pk.us[6] = f2bf(u1.z); pk.us[7] = f2bf(u1.w);
          *(uint4*)((char*)As + flat) = pk.v;
        }
      }
    }
    __syncthreads();

    bf16x8 af[4], bfr[4];
    for (int i = 0; i < 4; i++) {
      int off = (wr * 64 + i * 16 + (lane & 15)) * 32 + (lane >> 4) * 8;
      af[i] = *(const bf16x8*)&As[off];
    }
    for (int n = 0; n < 4; n++) {
      int off = (wc * 64 + n * 16 + (lane & 15)) * 32 + (lane >> 4) * 8;
      bfr[n] = *(const bf16x8*)&Bs[off];
    }
    for (int i = 0; i < 4; i++)
      for (int n = 0; n < 4; n++)
        acc[i][n] = __builtin_amdgcn_mfma_f32_16x16x32_bf16(af[i], bfr[n], acc[i][n], 0, 0, 0);
  }

  // epilogue: + bias, store bf16.  C/D layout: col = lane&15, row = (lane>>4)*4 + v
  for (int n = 0; n < 4; n++) {
    int gcol = nblk * 128 + wc * 64 + n * 16 + (lane & 15);
    float bb = b0[layer * XPW + gcol];
    for (int i = 0; i < 4; i++) {
      int rowBase = mblk * 128 + wr * 64 + i * 16 + (lane >> 4) * 4;
      for (int v = 0; v < 4; v++)
        xp[(size_t)(rowBase + v) * XPW + gcol] = f2bf(acc[i][n][v] + bb);
    }
  }
}

// ---------------- recurrence: 1 workgroup (4 waves, 256 thr) per (graph, dir)
// lane layout: j = wave*32 + (lane&31)  (0..127 = GRU unit), half = lane>>5 (K half)
// Each lane: 3 gate columns {j, 128+j, 256+j}, K in [half*64, half*64+64) as 32 f16x2 regs.
// K-half combine via __shfl_xor(32); h exchanged via ping-pong LDS, ONE raw s_barrier per
// step with lgkmcnt-only wait (vmcnt stays in flight -> xp prefetch / y stores overlap).
__global__ __launch_bounds__(256) void rec_kernel(
    const ushortT* __restrict__ xp,
    const float* __restrict__ Rf, const float* __restrict__ Rb,
    const float* __restrict__ bfw, const float* __restrict__ bbw,
    const int* __restrict__ L, ushortT* __restrict__ y, int layer)
{
  int g = blockIdx.x, dir = blockIdx.y;
  int Lg = L[g];
  if (Lg == 0) return;
  int tid = threadIdx.x;
  int wave = tid >> 6, lane = tid & 63;
  int jl = lane & 31, half = lane >> 5;
  int j = wave * 32 + jl;                 // 0..127

  __shared__ __align__(16) f16 hpk[2][128];

  const float* R  = (dir ? Rb : Rf) + (size_t)layer * U_DIM * TU;
  const float* b1 = (dir ? bbw : bfw) + layer * 2 * TU + TU;

  // recurrent weights into registers (f16x2 over k-pairs)
  f16x2 rz[32], rg[32], rh[32];
  #pragma unroll
  for (int m = 0; m < 32; ++m) {
    int k = half * 64 + 2 * m;
    const float* p0 = R + (size_t)k * TU;
    const float* p1 = p0 + TU;
    f16x2 a, b, c;
    a.x = (f16)p0[j];        a.y = (f16)p1[j];
    b.x = (f16)p0[128 + j];  b.y = (f16)p1[128 + j];
    c.x = (f16)p0[256 + j];  c.y = (f16)p1[256 + j];
    rz[m] = a; rg[m] = b; rh[m] = c;
  }
  float bz = half ? 0.0f : b1[j];
  float br = half ? 0.0f : b1[128 + j];
  float bh = half ? 0.0f : b1[256 + j];

  if (tid < 128) hpk[0][tid] = (f16)0.0f;
  float hreg = 0.0f;
  __syncthreads();

  size_t xbase = (size_t)g * NPER * XPW + (size_t)dir * TU;
  ushortT xzA = 0, xrA = 0, xhA = 0, xzB = 0, xrB = 0, xhB = 0;
  {
    int p0 = dir ? (Lg - 1) : 0;
    const ushortT* p = xp + xbase + (size_t)p0 * XPW;
    xzA = p[j]; xrA = p[128 + j]; xhA = p[256 + j];
    if (Lg > 1) {
      int p1 = dir ? (Lg - 2) : 1;
      const ushortT* q = xp + xbase + (size_t)p1 * XPW;
      xzB = q[j]; xrB = q[128 + j]; xhB = q[256 + j];
    }
  }

#define GRU_STEP(P, XZ, XR, XH, SS)                                              \
  {                                                                              \
    const int s_ = (SS);                                                         \
    float xzf = bf2f(XZ), xrf = bf2f(XR), xhf = bf2f(XH);                        \
    const int sp_ = s_ + 2;                                                      \
    if (sp_ < Lg) {                                                              \
      int pos2 = dir ? (Lg - 1 - sp_) : sp_;                                     \
      const ushortT* p_ = xp + xbase + (size_t)pos2 * XPW;                       \
      XZ = p_[j]; XR = p_[128 + j]; XH = p_[256 + j];                            \
    }                                                                            \
    const uint4* hv = (const uint4*)&hpk[P][half * 64];                          \
    uint32 hw[32];                                                               \
    _Pragma("unroll")                                                            \
    for (int q8 = 0; q8 < 8; ++q8) {                                             \
      uint4 v_ = hv[q8];                                                         \
      hw[4*q8] = v_.x; hw[4*q8+1] = v_.y; hw[4*q8+2] = v_.z; hw[4*q8+3] = v_.w;  \
    }                                                                            \
    float az0 = bz, ar0 = br, ah0 = bh, az1 = 0.f, ar1 = 0.f, ah1 = 0.f;         \
    _Pragma("unroll")                                                            \
    for (int m = 0; m < 32; m += 2) {                                            \
      az0 = dot2f(u2h(hw[m]),   rz[m],   az0);                                   \
      ar0 = dot2f(u2h(hw[m]),   rg[m],   ar0);                                   \
      ah0 = dot2f(u2h(hw[m]),   rh[m],   ah0);                                   \
      az1 = dot2f(u2h(hw[m+1]), rz[m+1], az1);                                   \
      ar1 = dot2f(u2h(hw[m+1]), rg[m+1], ar1);                                   \
      ah1 = dot2f(u2h(hw[m+1]), rh[m+1], ah1);                                   \
    }                                                                            \
    float hz = az0 + az1, hr = ar0 + ar1, hh = ah0 + ah1;                        \
    hz += __shfl_xor(hz, 32);                                                    \
    hr += __shfl_xor(hr, 32);                                                    \
    hh += __shfl_xor(hh, 32);                                                    \
    float z = rcpf(1.0f + __expf(-(xzf + hz)));                                  \
    float r = rcpf(1.0f + __expf(-(xrf + hr)));                                  \
    float ch = xhf + r * hh;                                                     \
    float e = __expf(2.0f * __builtin_fabsf(ch));                                \
    float th = 1.0f - 2.0f * rcpf(e + 1.0f);                                     \
    float cand = __builtin_copysignf(th, ch);                                    \
    float hnew = cand + z * (hreg - cand);                                       \
    hreg = hnew;                                                                 \
    if (half) {                                                                  \
      int pos_ = dir ? (Lg - 1 - s_) : s_;                                       \
      y[(size_t)(g * NPER + pos_) * D_DIM + dir * U_DIM + j] = f2bf(hnew);       \
    } else {                                                                     \
      hpk[(P) ^ 1][j] = (f16)hnew;                                               \
    }                                                                            \
    asm volatile("s_waitcnt lgkmcnt(0)" ::: "memory");                           \
    __builtin_amdgcn_sched_barrier(0);                                           \
    __builtin_amdgcn_s_barrier();                                                \
    __builtin_amdgcn_sched_barrier(0);                                           \
  }

  for (int s = 0; s < Lg; s += 2) {
    GRU_STEP(0, xzA, xrA, xhA, s);
    if (s + 1 < Lg) GRU_STEP(1, xzB, xrB, xhB, s + 1);
  }
#undef GRU_STEP
}

// ---------------- unpack: leaf -> y (bf16->f32), non-leaf -> states copy
__global__ __launch_bounds__(256) void unpack_kernel(
    const float* __restrict__ states, const int* __restrict__ pos,
    const ushortT* __restrict__ y, float* __restrict__ out)
{
  int node = blockIdx.x * 4 + (threadIdx.x >> 6);
  int lane = threadIdx.x & 63;
  int p = pos[node];
  int g = node >> 11;
  float4 v;
  if (p) {
    const ushortT* yp = y + (size_t)(g * NPER + p - 1) * D_DIM + lane * 4;
    v = make_float4(bf2f(yp[0]), bf2f(yp[1]), bf2f(yp[2]), bf2f(yp[3]));
  } else {
    v = *(const float4*)(states + (size_t)node * D_DIM + lane * 4);
  }
  *(float4*)(out + (size_t)node * D_DIM + lane * 4) = v;
}

extern "C" void kernel_launch(void* const* d_in, const int* in_sizes, int n_in,
                              void* d_out, int out_size, void* d_ws, size_t ws_size,
                              hipStream_t stream) {
  const float* states = (const float*)d_in[0];
  const int*   pos    = (const int*)d_in[1];
  // d_in[2] graph_sizes (uniform 2048), d_in[3] training (0) — unused
  const float* Kf  = (const float*)d_in[4];
  const float* Rf  = (const float*)d_in[5];
  const float* bfw = (const float*)d_in[6];
  const float* Kb  = (const float*)d_in[7];
  const float* Rb  = (const float*)d_in[8];
  const float* bbw = (const float*)d_in[9];

  char* ws = (char*)d_ws;
  // layout: L(256B) | nodeof(512KB) | Wt(768KB) | b0(6KB) | xp(201.3MB) | y(67.1MB)  ~= 270MB
  int*     L      = (int*)(ws + 0);
  int*     nodeof = (int*)(ws + 256);
  ushortT* Wt     = (ushortT*)(ws + 524544);
  float*   b0     = (float*)(ws + 1310976);
  ushortT* xp     = (ushortT*)(ws + 1317120);
  ushortT* y      = (ushortT*)(ws + 202643712);

  prep_kernel<<<1542, 256, 0, stream>>>(Kf, Kb, bfw, bbw, Wt, b0);
  nodeofL_kernel<<<64, 256, 0, stream>>>(pos, nodeof, L);

  dim3 ggrid(1024, 6);
  dim3 rgrid(64, 2);

  // layer 0
  gemm_kernel<<<ggrid, 256, 0, stream>>>(states, (const ushortT*)nullptr, Wt, b0, nodeof, L, xp, 0, 0);
  rec_kernel<<<rgrid, 256, 0, stream>>>(xp, Rf, Rb, bfw, bbw, L, y, 0);
  // layer 1
  gemm_kernel<<<ggrid, 256, 0, stream>>>(states, y, Wt, b0, nodeof, L, xp, 1, 1);
  rec_kernel<<<rgrid, 256, 0, stream>>>(xp, Rf, Rb, bfw, bbw, L, y, 1);

  unpack_kernel<<<32768, 256, 0, stream>>>(states, pos, y, (float*)d_out);
}

// Round 5
// 1267.687 us; speedup vs baseline: 1.2058x; 1.0237x over previous
//
#include <hip/hip_runtime.h>
#include <hip/hip_bf16.h>

#define B_GRAPHS 64
#define NPER     2048
#define T_NODES  (B_GRAPHS*NPER)
#define D_DIM    256
#define U_DIM    128
#define TU       384   // 3*U
#define XPW      768   // 2*TU (fwd|bwd)

typedef unsigned short ushortT;
typedef unsigned int   uint32;

typedef __attribute__((ext_vector_type(4))) float  f32x4;
typedef __attribute__((ext_vector_type(8))) __bf16 bf16x8;
typedef _Float16 f16;
typedef __attribute__((ext_vector_type(2))) _Float16 f16x2;

#define GAS __attribute__((address_space(1)))

static __device__ __forceinline__ ushortT f2bf(float f) {
  union { float f; uint32 u; } a; a.f = f;
  uint32 u = a.u;
  return (ushortT)((u + 0x7fffu + ((u >> 16) & 1u)) >> 16);   // RTNE
}
static __device__ __forceinline__ float bf2f(ushortT h) {
  union { uint32 u; float f; } a; a.u = ((uint32)h) << 16; return a.f;
}
static __device__ __forceinline__ f16x2 u2h(uint32 u) {
  union { uint32 u; f16x2 h; } x; x.u = u; return x.h;
}
static __device__ __forceinline__ float dot2f(f16x2 a, f16x2 b, float c) {
#if __has_builtin(__builtin_amdgcn_fdot2)
  return __builtin_amdgcn_fdot2(a, b, c, false);
#else
  return c + (float)a.x * (float)b.x + (float)a.y * (float)b.y;
#endif
}
static __device__ __forceinline__ float rcpf(float x) {
#if __has_builtin(__builtin_amdgcn_rcpf)
  return __builtin_amdgcn_rcpf(x);
#else
  return 1.0f / x;
#endif
}

// force global (addrspace 1) access -> global_load_ushort / global_store_short
// (vmcnt-only; a flat_* lowering would also count against lgkmcnt and serialize
// the per-step lgkmcnt(0) drain against HBM latency)
static __device__ __forceinline__ ushortT gload_u16(const ushortT* p) {
  return *(const GAS ushortT*)p;
}
static __device__ __forceinline__ void gstore_u16(ushortT* p, ushortT v) {
  *(GAS ushortT*)p = v;
}

// sum over lane pairs (l, l^32): round-2-proven path (ds_bpermute via __shfl_xor)
static __device__ __forceinline__ float xor32_sum(float v) {
  return v + __shfl_xor(v, 32);
}

// ---------------- prep: Wt[2][768][256] bf16 (transposed concat of K_fwd|K_bwd), b0[2][768] f32
__global__ __launch_bounds__(256) void prep_kernel(
    const float* __restrict__ Kf, const float* __restrict__ Kb,
    const float* __restrict__ bfw, const float* __restrict__ bbw,
    ushortT* __restrict__ Wt, float* __restrict__ b0)
{
  int idx = blockIdx.x * 256 + threadIdx.x;
  if (idx < 2 * XPW * D_DIM) {
    int l = idx / (XPW * D_DIM);
    int rem = idx % (XPW * D_DIM);
    int c = rem / D_DIM, k = rem % D_DIM;
    float v = (c < TU) ? Kf[(size_t)l * D_DIM * TU + (size_t)k * TU + c]
                       : Kb[(size_t)l * D_DIM * TU + (size_t)k * TU + (c - TU)];
    Wt[idx] = f2bf(v);
  } else {
    int i2 = idx - 2 * XPW * D_DIM;
    if (i2 < 2 * XPW) {
      int l = i2 / XPW, c = i2 % XPW;
      b0[i2] = (c < TU) ? bfw[l * 2 * TU + c] : bbw[l * 2 * TU + (c - TU)];
    }
  }
}

// ---------------- nodeof[g][slot] = node index ; L[g] = leaf count (positions are a perm of 1..L)
__global__ __launch_bounds__(256) void nodeofL_kernel(
    const int* __restrict__ pos, int* __restrict__ nodeof, int* __restrict__ L)
{
  int g = blockIdx.x, tid = threadIdx.x;
  __shared__ int red[256];
  int cnt = 0;
  for (int i = 0; i < NPER / 256; ++i) {
    int t = g * NPER + i * 256 + tid;
    int p = pos[t];
    if (p) { nodeof[g * NPER + p - 1] = t; cnt++; }
  }
  red[tid] = cnt; __syncthreads();
  for (int s = 128; s > 0; s >>= 1) {
    if (tid < s) red[tid] += red[tid + s];
    __syncthreads();
  }
  if (tid == 0) L[g] = red[0];
}

#if __has_builtin(__builtin_amdgcn_global_load_lds)
#define GLD_LDS(gsrc, ldst) \
  __builtin_amdgcn_global_load_lds((const GAS void*)(gsrc), \
                                   (__attribute__((address_space(3))) void*)(ldst), 16, 0, 0)
#define HAVE_GLD_LDS 1
#else
#define HAVE_GLD_LDS 0
#endif

// ---------------- xp[row][768] = A[row][0..255] @ Wt^T + b0   (bf16 MFMA, 128x128 tiles, BK=32)
// mode 0: A row r gathered from states (f32 -> bf16) via nodeof ; mode 1: A = dense bf16 (y)
__global__ __launch_bounds__(256) void gemm_kernel(
    const float* __restrict__ statesA, const ushortT* __restrict__ Adense,
    const ushortT* __restrict__ Wt, const float* __restrict__ b0,
    const int* __restrict__ nodeof, const int* __restrict__ L,
    ushortT* __restrict__ xp, int layer, int mode)
{
  int mblk = blockIdx.x, nblk = blockIdx.y;
  int g = mblk >> 4;
  int sBase = (mblk & 15) << 7;
  int Lg = L[g];
  if (sBase >= Lg) return;   // whole row-block is padding

  __shared__ __align__(16) ushortT As[128 * 32];
  __shared__ __align__(16) ushortT Bs[128 * 32];

  int tid = threadIdx.x;
  int lane = tid & 63, wid = tid >> 6;
  int wr = wid >> 1, wc = wid & 1;
  f32x4 acc[4][4];
  for (int i = 0; i < 4; i++) for (int n = 0; n < 4; n++) acc[i][n] = (f32x4){0.f,0.f,0.f,0.f};

  for (int kb = 0; kb < 8; ++kb) {
    __syncthreads();
    // stage B: Wt tile [128 cols][32 k] (Wt is pre-transposed: row=col, 512B row stride)
    for (int c = 0; c < 2; ++c) {
      int flat = c * 4096 + tid * 16;
      int col = flat >> 6;
      size_t srcB = ((size_t)(layer * XPW + nblk * 128 + col)) * 512 + kb * 64 + (flat & 63);
#if HAVE_GLD_LDS
      GLD_LDS((const char*)Wt + srcB, (char*)Bs + c * 4096 + wid * 1024);
#else
      *(uint4*)((char*)Bs + flat) = *(const uint4*)((const char*)Wt + srcB);
#endif
    }
    // stage A
    if (mode) {
      for (int c = 0; c < 2; ++c) {
        int flat = c * 4096 + tid * 16;
        int row = flat >> 6;
        size_t srcA = ((size_t)(mblk * 128 + row)) * 512 + kb * 64 + (flat & 63);
#if HAVE_GLD_LDS
        GLD_LDS((const char*)Adense + srcA, (char*)As + c * 4096 + wid * 1024);
#else
        *(uint4*)((char*)As + flat) = *(const uint4*)((const char*)Adense + srcA);
#endif
      }
    } else {
      for (int c = 0; c < 2; ++c) {
        int flat = c * 4096 + tid * 16;
        int row = flat >> 6;
        int s = sBase + row;
        if (s < Lg) {
          int nt = nodeof[g * NPER + s];
          const float* sp = statesA + (size_t)nt * D_DIM + kb * 32 + ((flat & 63) >> 1);
          float4 u0 = *(const float4*)sp;
          float4 u1 = *(const float4*)(sp + 4);
          union { ushortT us[8]; uint4 v; } pk;
          pk.us[0] = f2bf(u0.x); pk.us[1] = f2bf(u0.y); pk.us[2] = f2bf(u0.z); pk.us[3] = f2bf(u0.w);
          pk.us[4] = f2bf(u1.x); pk.us[5] = f2bf(u1.y); pk.us[6] = f2bf(u1.z); pk.us[7] = f2bf(u1.w);
          *(uint4*)((char*)As + flat) = pk.v;
        }
      }
    }
    __syncthreads();

    bf16x8 af[4], bfr[4];
    for (int i = 0; i < 4; i++) {
      int off = (wr * 64 + i * 16 + (lane & 15)) * 32 + (lane >> 4) * 8;
      af[i] = *(const bf16x8*)&As[off];
    }
    for (int n = 0; n < 4; n++) {
      int off = (wc * 64 + n * 16 + (lane & 15)) * 32 + (lane >> 4) * 8;
      bfr[n] = *(const bf16x8*)&Bs[off];
    }
    for (int i = 0; i < 4; i++)
      for (int n = 0; n < 4; n++)
        acc[i][n] = __builtin_amdgcn_mfma_f32_16x16x32_bf16(af[i], bfr[n], acc[i][n], 0, 0, 0);
  }

  // epilogue: + bias, store bf16.  C/D layout: col = lane&15, row = (lane>>4)*4 + v
  for (int n = 0; n < 4; n++) {
    int gcol = nblk * 128 + wc * 64 + n * 16 + (lane & 15);
    float bb = b0[layer * XPW + gcol];
    for (int i = 0; i < 4; i++) {
      int rowBase = mblk * 128 + wr * 64 + i * 16 + (lane >> 4) * 4;
      for (int v = 0; v < 4; v++)
        xp[(size_t)(rowBase + v) * XPW + gcol] = f2bf(acc[i][n][v] + bb);
    }
  }
}

// ---------------- recurrence: 1 workgroup (4 waves, 256 thr) per (graph, dir)
// lane layout: j = wave*32 + (lane&31)  (0..127 = GRU unit), half = lane>>5 (K half)
// Each lane: 3 gate columns {j, 128+j, 256+j}, K in [half*64, half*64+64) as 32 f16x2 regs.
// K-half combine via __shfl_xor(32); h exchanged via ping-pong LDS, ONE raw s_barrier per
// step with lgkmcnt-only wait. xp loads / y stores forced to addrspace(1) so they are
// vmcnt-only and stay in flight across the barrier. Prefetch depth 4.
__global__ __launch_bounds__(256) void rec_kernel(
    const ushortT* __restrict__ xp,
    const float* __restrict__ Rf, const float* __restrict__ Rb,
    const float* __restrict__ bfw, const float* __restrict__ bbw,
    const int* __restrict__ L, ushortT* __restrict__ y, int layer)
{
  int g = blockIdx.x, dir = blockIdx.y;
  int Lg = L[g];
  if (Lg == 0) return;
  int tid = threadIdx.x;
  int wave = tid >> 6, lane = tid & 63;
  int jl = lane & 31, half = lane >> 5;
  int j = wave * 32 + jl;                 // 0..127

  __shared__ __align__(16) f16 hpk[2][128];

  const float* R  = (dir ? Rb : Rf) + (size_t)layer * U_DIM * TU;
  const float* b1 = (dir ? bbw : bfw) + layer * 2 * TU + TU;

  // recurrent weights into registers (f16x2 over k-pairs)
  f16x2 rz[32], rg[32], rh[32];
  #pragma unroll
  for (int m = 0; m < 32; ++m) {
    int k = half * 64 + 2 * m;
    const float* p0 = R + (size_t)k * TU;
    const float* p1 = p0 + TU;
    f16x2 a, b, c;
    a.x = (f16)p0[j];        a.y = (f16)p1[j];
    b.x = (f16)p0[128 + j];  b.y = (f16)p1[128 + j];
    c.x = (f16)p0[256 + j];  c.y = (f16)p1[256 + j];
    rz[m] = a; rg[m] = b; rh[m] = c;
  }
  float bz = half ? 0.0f : b1[j];
  float br = half ? 0.0f : b1[128 + j];
  float bh = half ? 0.0f : b1[256 + j];

  if (tid < 128) hpk[0][tid] = (f16)0.0f;
  float hreg = 0.0f;
  __syncthreads();

  size_t xbase = (size_t)g * NPER * XPW + (size_t)dir * TU;
  // prefetch depth 4: sets 0..3 hold xp for steps s..s+3 (rolling, reloaded +4 ahead)
  ushortT xz0=0,xr0=0,xh0=0, xz1=0,xr1=0,xh1=0, xz2=0,xr2=0,xh2=0, xz3=0,xr3=0,xh3=0;
  {
    const ushortT* p;
    if (0 < Lg) { p = xp + xbase + (size_t)(dir ? Lg-1 : 0) * XPW;
                  xz0 = gload_u16(p+j); xr0 = gload_u16(p+128+j); xh0 = gload_u16(p+256+j); }
    if (1 < Lg) { p = xp + xbase + (size_t)(dir ? Lg-2 : 1) * XPW;
                  xz1 = gload_u16(p+j); xr1 = gload_u16(p+128+j); xh1 = gload_u16(p+256+j); }
    if (2 < Lg) { p = xp + xbase + (size_t)(dir ? Lg-3 : 2) * XPW;
                  xz2 = gload_u16(p+j); xr2 = gload_u16(p+128+j); xh2 = gload_u16(p+256+j); }
    if (3 < Lg) { p = xp + xbase + (size_t)(dir ? Lg-4 : 3) * XPW;
                  xz3 = gload_u16(p+j); xr3 = gload_u16(p+128+j); xh3 = gload_u16(p+256+j); }
  }

#define GRU_STEP(P, XZ, XR, XH, SS)                                              \
  {                                                                              \
    const int s_ = (SS);                                                         \
    float xzf = bf2f(XZ), xrf = bf2f(XR), xhf = bf2f(XH);                        \
    const int sp_ = s_ + 4;                                                      \
    if (sp_ < Lg) {                                                              \
      int pos2 = dir ? (Lg - 1 - sp_) : sp_;                                     \
      const ushortT* p_ = xp + xbase + (size_t)pos2 * XPW;                       \
      XZ = gload_u16(p_ + j);                                                    \
      XR = gload_u16(p_ + 128 + j);                                              \
      XH = gload_u16(p_ + 256 + j);                                              \
    }                                                                            \
    const uint4* hv = (const uint4*)&hpk[P][half * 64];                          \
    uint32 hw[32];                                                               \
    _Pragma("unroll")                                                            \
    for (int q8 = 0; q8 < 8; ++q8) {                                             \
      uint4 v_ = hv[q8];                                                         \
      hw[4*q8] = v_.x; hw[4*q8+1] = v_.y; hw[4*q8+2] = v_.z; hw[4*q8+3] = v_.w;  \
    }                                                                            \
    float az0 = bz, ar0 = br, ah0 = bh, az1 = 0.f, ar1 = 0.f, ah1 = 0.f;         \
    _Pragma("unroll")                                                            \
    for (int m = 0; m < 32; m += 2) {                                            \
      az0 = dot2f(u2h(hw[m]),   rz[m],   az0);                                   \
      ar0 = dot2f(u2h(hw[m]),   rg[m],   ar0);                                   \
      ah0 = dot2f(u2h(hw[m]),   rh[m],   ah0);                                   \
      az1 = dot2f(u2h(hw[m+1]), rz[m+1], az1);                                   \
      ar1 = dot2f(u2h(hw[m+1]), rg[m+1], ar1);                                   \
      ah1 = dot2f(u2h(hw[m+1]), rh[m+1], ah1);                                   \
    }                                                                            \
    float hz = xor32_sum(az0 + az1);                                             \
    float hr = xor32_sum(ar0 + ar1);                                             \
    float hh = xor32_sum(ah0 + ah1);                                             \
    float z = rcpf(1.0f + __expf(-(xzf + hz)));                                  \
    float r = rcpf(1.0f + __expf(-(xrf + hr)));                                  \
    float ch = xhf + r * hh;                                                     \
    float e = __expf(2.0f * __builtin_fabsf(ch));                                \
    float th = 1.0f - 2.0f * rcpf(e + 1.0f);                                     \
    float cand = __builtin_copysignf(th, ch);                                    \
    float hnew = cand + z * (hreg - cand);                                       \
    hreg = hnew;                                                                 \
    if (half) {                                                                  \
      int pos_ = dir ? (Lg - 1 - s_) : s_;                                       \
      gstore_u16(y + (size_t)(g * NPER + pos_) * D_DIM + dir * U_DIM + j,        \
                 f2bf(hnew));                                                    \
    } else {                                                                     \
      hpk[(P) ^ 1][j] = (f16)hnew;                                               \
    }                                                                            \
    asm volatile("s_waitcnt lgkmcnt(0)" ::: "memory");                           \
    __builtin_amdgcn_sched_barrier(0);                                           \
    __builtin_amdgcn_s_barrier();                                                \
    __builtin_amdgcn_sched_barrier(0);                                           \
  }

  for (int s = 0; s < Lg; s += 4) {
    GRU_STEP(0, xz0, xr0, xh0, s);
    if (s + 1 < Lg) GRU_STEP(1, xz1, xr1, xh1, s + 1);
    if (s + 2 < Lg) GRU_STEP(0, xz2, xr2, xh2, s + 2);
    if (s + 3 < Lg) GRU_STEP(1, xz3, xr3, xh3, s + 3);
  }
#undef GRU_STEP
}

// ---------------- unpack: leaf -> y (bf16->f32), non-leaf -> states copy
__global__ __launch_bounds__(256) void unpack_kernel(
    const float* __restrict__ states, const int* __restrict__ pos,
    const ushortT* __restrict__ y, float* __restrict__ out)
{
  int node = blockIdx.x * 4 + (threadIdx.x >> 6);
  int lane = threadIdx.x & 63;
  int p = pos[node];
  int g = node >> 11;
  float4 v;
  if (p) {
    const ushortT* yp = y + (size_t)(g * NPER + p - 1) * D_DIM + lane * 4;
    v = make_float4(bf2f(yp[0]), bf2f(yp[1]), bf2f(yp[2]), bf2f(yp[3]));
  } else {
    v = *(const float4*)(states + (size_t)node * D_DIM + lane * 4);
  }
  *(float4*)(out + (size_t)node * D_DIM + lane * 4) = v;
}

extern "C" void kernel_launch(void* const* d_in, const int* in_sizes, int n_in,
                              void* d_out, int out_size, void* d_ws, size_t ws_size,
                              hipStream_t stream) {
  const float* states = (const float*)d_in[0];
  const int*   pos    = (const int*)d_in[1];
  // d_in[2] graph_sizes (uniform 2048), d_in[3] training (0) — unused
  const float* Kf  = (const float*)d_in[4];
  const float* Rf  = (const float*)d_in[5];
  const float* bfw = (const float*)d_in[6];
  const float* Kb  = (const float*)d_in[7];
  const float* Rb  = (const float*)d_in[8];
  const float* bbw = (const float*)d_in[9];

  char* ws = (char*)d_ws;
  // layout: L(256B) | nodeof(512KB) | Wt(768KB) | b0(6KB) | xp(201.3MB) | y(67.1MB)  ~= 270MB
  int*     L      = (int*)(ws + 0);
  int*     nodeof = (int*)(ws + 256);
  ushortT* Wt     = (ushortT*)(ws + 524544);
  float*   b0     = (float*)(ws + 1310976);
  ushortT* xp     = (ushortT*)(ws + 1317120);
  ushortT* y      = (ushortT*)(ws + 202643712);

  prep_kernel<<<1542, 256, 0, stream>>>(Kf, Kb, bfw, bbw, Wt, b0);
  nodeofL_kernel<<<64, 256, 0, stream>>>(pos, nodeof, L);

  dim3 ggrid(1024, 6);
  dim3 rgrid(64, 2);

  // layer 0
  gemm_kernel<<<ggrid, 256, 0, stream>>>(states, (const ushortT*)nullptr, Wt, b0, nodeof, L, xp, 0, 0);
  rec_kernel<<<rgrid, 256, 0, stream>>>(xp, Rf, Rb, bfw, bbw, L, y, 0);
  // layer 1
  gemm_kernel<<<ggrid, 256, 0, stream>>>(states, y, Wt, b0, nodeof, L, xp, 1, 1);
  rec_kernel<<<rgrid, 256, 0, stream>>>(xp, Rf, Rb, bfw, bbw, L, y, 1);

  unpack_kernel<<<32768, 256, 0, stream>>>(states, pos, y, (float*)d_out);
}